// Round 6
// baseline (189.928 us; speedup 1.0000x reference)
//
#include <hip/hip_runtime.h>
#include <hip/hip_bf16.h>
#include <cstdint>
#include <cstddef>

// B=8, S=512, D=768, HEADS=16, HD=64
// Pipeline (3 kernels):
//   prep:      cast hidden->bf16, sincos table, LDS-tiled W transpose->Wt bf16
//   gemm_rope: 4096x2048x768 bf16 MFMA + bias + RoPE (shfl_xor pair) epilogue,
//              writes Q,K head-major (b,h,s,64) bf16
//   logits:    128 batched 512x512x64 MFMA, global_load_lds + XOR-swizzled LDS,
//              mask epilogue, tri_mask fused into h==0 blocks
// Tolerance ~2e10 absmax (NEG=1e12) -> bf16 numerically free.
// R5: nt stores reverted (208.4 -> 193.7; nt defeats L2 write-combining).
// R6: XCD swizzle: 190.1.  R7: BK=64: 185.2 (-4.9, drain-cost theory held).
// R8: gemm_rope tile 128x128 -> 128x64, grid 512 -> 1024 = 4 blocks/CU (was 2).
//     Barrier drains are hidden by OTHER resident blocks (m114 implicit
//     overlap needs ~3 blocks/CU; barriers stall all waves within a block).
//     LDS 24KB/block; B-panel (3.1MB Wt) refetch is L2-resident, negligible.

#define NEGV 1.0e12f

typedef short bf16x8 __attribute__((ext_vector_type(8)));
typedef float f32x4  __attribute__((ext_vector_type(4)));

static __device__ __forceinline__ short f2b(float x) {
    __hip_bfloat16 h = __float2bfloat16(x);
    union { __hip_bfloat16 h; short s; } u; u.h = h; return u.s;
}
static __device__ __forceinline__ float b2f(short s) {
    union { short s; __hip_bfloat16 h; } u; u.s = s; return __bfloat162float(u.h);
}
// async global->LDS: per-lane global addr, LDS dest = wave-uniform base + lane*16
static __device__ __forceinline__ void gload16(const short* g, short* l) {
    __builtin_amdgcn_global_load_lds(
        (const __attribute__((address_space(1))) void*)g,
        (__attribute__((address_space(3))) void*)l, 16, 0, 0);
}

// ---------------------------------------------------------------------------
// 1) prep: blocks [0,1536) cast hidden; [1536,1600) sincos table;
//          [1600,1984) 64x64 LDS-tiled W transpose (fp32 KxN -> bf16 NxK)
// ---------------------------------------------------------------------------
__global__ __launch_bounds__(256) void prep_kernel(const float* __restrict__ hidden,
                                                   const float* __restrict__ W,
                                                   short* __restrict__ Xb,
                                                   short* __restrict__ Wt,
                                                   float* __restrict__ SinT,
                                                   float* __restrict__ CosT) {
    __shared__ short T[64 * 68];
    int blk = blockIdx.x, tid = threadIdx.x;
    if (blk < 1536) {                          // 393,216 threads x 8 floats
        int t = blk * 256 + tid;
        const float4* hp = (const float4*)hidden;
        float4 a = hp[t * 2], c = hp[t * 2 + 1];
        bf16x8 v;
        v[0] = f2b(a.x); v[1] = f2b(a.y); v[2] = f2b(a.z); v[3] = f2b(a.w);
        v[4] = f2b(c.x); v[5] = f2b(c.y); v[6] = f2b(c.z); v[7] = f2b(c.w);
        *(bf16x8*)(Xb + t * 8) = v;
    } else if (blk < 1600) {                   // 16,384 table entries
        int u = (blk - 1536) * 256 + tid;
        int s = u >> 5, i = u & 31;
        float ang = (float)s * exp2f(-0.4152410118609203f * (float)i); // log2(1e4)/32
        float sn, cs; __sincosf(ang, &sn, &cs);
        SinT[u] = sn; CosT[u] = cs;
    } else {                                   // 384 transpose tiles
        int tb = blk - 1600;
        int k0 = (tb % 12) * 64, n0 = (tb / 12) * 64;
        int r = tid >> 2, cb = (tid & 3) * 4;
#pragma unroll
        for (int q = 0; q < 4; ++q) {
            int c = cb + q * 16;
            float4 v = *(const float4*)(W + (size_t)(k0 + r) * 2048 + n0 + c);
            short* tp = T + r * 68 + c;
            tp[0] = f2b(v.x); tp[1] = f2b(v.y); tp[2] = f2b(v.z); tp[3] = f2b(v.w);
        }
        __syncthreads();
        int n = tid >> 2, kc = (tid & 3) * 16;
        bf16x8 o0, o1;
#pragma unroll
        for (int j = 0; j < 8; ++j) {
            o0[j] = T[(kc + j) * 68 + n];
            o1[j] = T[(kc + 8 + j) * 68 + n];
        }
        short* wp = Wt + (size_t)(n0 + n) * 768 + k0 + kc;
        *(bf16x8*)wp = o0;
        *(bf16x8*)(wp + 8) = o1;
    }
}

// ---------------------------------------------------------------------------
// 2) gemm_rope: C=A@Wt^T+bias (4096x2048x768), 128x64 tile (R8), BK=64,
//    grid 1024 = 4 blocks/CU. 4 waves, wave tile 32x64, acc[2][4].
//    global_load_lds staging; LDS rows 64 shorts (128B) with XOR swizzle:
//    row r position p holds global chunk p^(r&7); staged via pre-swizzled
//    global src chunk ((l&7)^(l>>3)), frag read chunk (kk*4+quad)^(r16&7)
//    -> 2-way bank conflicts (free).
//    Epilogue: bias + RoPE via __shfl_xor(v,1), store Q/K head-major bf16.
//    XCD-chunked wgid swizzle (1024 = 8 XCD * 128); consecutive logical blks
//    share the A m-panel -> L2-local.
// ---------------------------------------------------------------------------
__global__ __launch_bounds__(256) void gemm_rope(const short* __restrict__ A,
                                                 const short* __restrict__ Bt,
                                                 const float* __restrict__ bias,
                                                 const float* __restrict__ SinT,
                                                 const float* __restrict__ CosT,
                                                 short* __restrict__ Qb,
                                                 short* __restrict__ Kb) {
    __shared__ short As[128 * 64];
    __shared__ short Bs[64 * 64];
    const int blk = (blockIdx.x & 7) * 128 + (blockIdx.x >> 3);  // XCD-chunked
    const int m0 = (blk >> 5) * 128;          // 32 m-tiles
    const int n0 = (blk & 31) * 64;           // 32 n-tiles
    const int tid  = threadIdx.x;
    const int wave = tid >> 6, lane = tid & 63;
    const int quad = lane >> 4, r16 = lane & 15;
    const int wm = wave * 32;                 // wave rows [wm, wm+32)

    // staging: call j covers rows j*32 + wave*8 + (l>>3); global chunk
    // pre-swizzled (l&7)^(l>>3); LDS dest linear (wave-uniform + lane*16B).
    const int sc  = ((lane & 7) ^ (lane >> 3)) * 8;   // shorts
    const int rst = wave * 8 + (lane >> 3);
    const short* gA = A  + (size_t)(m0 + rst) * 768 + sc;
    const short* gB = Bt + (size_t)(n0 + rst) * 768 + sc;
    short* lA = As + (wave * 8) * 64;
    short* lB = Bs + (wave * 8) * 64;

    const int sw8 = r16 & 7;                  // frag-read swizzle key (row&7)

    f32x4 acc[2][4] = {};
    for (int k0 = 0; k0 < 768; k0 += 64) {
        __syncthreads();                      // protect LDS overwrite
#pragma unroll
        for (int j = 0; j < 4; ++j)           // A: 128 rows
            gload16(gA + (size_t)(j * 32) * 768 + k0, lA + j * 32 * 64);
#pragma unroll
        for (int j = 0; j < 2; ++j)           // B: 64 rows
            gload16(gB + (size_t)(j * 32) * 768 + k0, lB + j * 32 * 64);
        __syncthreads();                      // vmcnt drain: tile ready

#pragma unroll
        for (int kk = 0; kk < 2; ++kk) {
            bf16x8 af[2], bfr[4];
#pragma unroll
            for (int mi = 0; mi < 2; ++mi)
                af[mi] = *(const bf16x8*)(As + (wm + mi * 16 + r16) * 64
                                             + ((kk * 4 + quad) ^ sw8) * 8);
#pragma unroll
            for (int ni = 0; ni < 4; ++ni)
                bfr[ni] = *(const bf16x8*)(Bs + (ni * 16 + r16) * 64
                                              + ((kk * 4 + quad) ^ sw8) * 8);
#pragma unroll
            for (int mi = 0; mi < 2; ++mi)
#pragma unroll
                for (int ni = 0; ni < 4; ++ni)
                    acc[mi][ni] = __builtin_amdgcn_mfma_f32_16x16x32_bf16(
                        af[mi], bfr[ni], acc[mi][ni], 0, 0, 0);
        }
    }

    // epilogue: bias + RoPE + head-major store
    const int b     = m0 >> 9;
    const int s0l   = (m0 & 511) + wm + quad * 4;
    const int h     = n0 >> 7;                 // head index
    const int which = (n0 >> 6) & 1;           // 0 -> Q half, 1 -> K half
    short* dstT = (which ? Kb : Qb) + (size_t)(b * 16 + h) * 512 * 64;
    const float sgn = (r16 & 1) ? 1.0f : -1.0f;
#pragma unroll
    for (int ni = 0; ni < 4; ++ni) {
        int col = n0 + ni * 16 + r16;
        float bv = bias[col];
        int d  = ni * 16 + r16;                // head-dim index 0..63
        int ii = d >> 1;
#pragma unroll
        for (int mi = 0; mi < 2; ++mi)
#pragma unroll
            for (int r = 0; r < 4; ++r) {
                int s = s0l + mi * 16 + r;
                float v  = acc[mi][ni][r] + bv;
                float pv = __shfl_xor(v, 1);   // partner element of the RoPE pair
                float sn = SinT[s * 32 + ii];
                float cs = CosT[s * 32 + ii];
                dstT[(size_t)s * 64 + d] = f2b(v * cs + sgn * pv * sn);
            }
    }
}

// ---------------------------------------------------------------------------
// 3) logits: per (b,h, 128x128 tile) Q@K^T (K=64). global_load_lds staging,
//    XOR swizzle chunk(r,c)->r*8+(c^(r&7)) -> 2-way frag reads (free).
//    Epilogue: /8 - rowNeg - colNeg - causal; tri_mask fused at h==0.
//    XCD-chunked wgid swizzle (2048 = 8 XCD * 256).
// ---------------------------------------------------------------------------
__global__ __launch_bounds__(256) void logits_kernel(const short* __restrict__ Qb,
                                                     const short* __restrict__ Kb,
                                                     const int* __restrict__ tok,
                                                     float* __restrict__ out,
                                                     float* __restrict__ out2) {
    __shared__ short Qs[128 * 64];
    __shared__ short Ks[128 * 64];
    __shared__ float rowNeg[128];
    __shared__ float colNeg[128];

    int blk = (blockIdx.x & 7) * 256 + (blockIdx.x >> 3);  // XCD-chunked
    int nt = blk & 3, mt = (blk >> 2) & 3, bh = blk >> 4;
    int b = bh >> 4, h = bh & 15;
    int m0 = mt * 128, n0 = nt * 128;

    const int tid  = threadIdx.x;
    const int wave = tid >> 6, lane = tid & 63;
    const int quad = lane >> 4, r16 = lane & 15;
    const int wm = (wave >> 1) * 64, wn = (wave & 1) * 64;

    // staging: waves 0,1 -> Q; waves 2,3 -> K. 8 calls x 64 chunks each.
    const short* gsrc = (wave < 2)
        ? Qb + ((size_t)bh * 512 + m0) * 64
        : Kb + ((size_t)bh * 512 + n0) * 64;
    short* ldst = (wave < 2) ? Qs : Ks;
    const int wv = wave & 1;
    const int gc = ((lane & 7) ^ (lane >> 3)) * 8;   // swizzled chunk col, shorts
    const int rl = wv * 64 + (lane >> 3);            // + j*8 per call
#pragma unroll
    for (int j = 0; j < 8; ++j)
        gload16(gsrc + (rl + j * 8) * 64 + gc, ldst + wv * 4096 + j * 512);

    if (tid < 128)      rowNeg[tid]       = (tok[b * 512 + m0 + tid] > 0) ? 0.f : NEGV;
    else if (tid < 256) colNeg[tid - 128] = (tok[b * 512 + n0 + (tid - 128)] > 0) ? 0.f : NEGV;
    __syncthreads();

    const int sw8 = r16 & 7;              // frag swizzle key (r&7 == r16&7)
    f32x4 acc[4][4] = {};
#pragma unroll
    for (int kb = 0; kb < 2; ++kb) {      // kk = kb*32 -> chunkcol quad + kb*4
        bf16x8 af[4], bfr[4];
#pragma unroll
        for (int mi = 0; mi < 4; ++mi)
            af[mi] = *(const bf16x8*)(Qs + (wm + mi * 16 + r16) * 64
                                         + ((quad + kb * 4) ^ sw8) * 8);
#pragma unroll
        for (int ni = 0; ni < 4; ++ni)
            bfr[ni] = *(const bf16x8*)(Ks + (wn + ni * 16 + r16) * 64
                                          + ((quad + kb * 4) ^ sw8) * 8);
#pragma unroll
        for (int mi = 0; mi < 4; ++mi)
#pragma unroll
            for (int ni = 0; ni < 4; ++ni)
                acc[mi][ni] = __builtin_amdgcn_mfma_f32_16x16x32_bf16(
                    af[mi], bfr[ni], acc[mi][ni], 0, 0, 0);
    }

    float* obase = out + (size_t)bh * 512 * 512;
#pragma unroll
    for (int mi = 0; mi < 4; ++mi)
#pragma unroll
        for (int ni = 0; ni < 4; ++ni) {
            int n = n0 + wn + ni * 16 + r16;
            float cn = colNeg[n - n0];
#pragma unroll
            for (int r = 0; r < 4; ++r) {
                int m = m0 + wm + mi * 16 + quad * 4 + r;
                float v = acc[mi][ni][r] * 0.125f - rowNeg[m - m0] - cn
                          - ((m > n) ? NEGV : 0.0f);
                obase[(size_t)m * 512 + n] = v;
            }
        }

    if (h == 0) {    // fused tri_mask
        float* o2 = out2 + (size_t)b * 512 * 512;
#pragma unroll
        for (int mi = 0; mi < 4; ++mi)
#pragma unroll
            for (int ni = 0; ni < 4; ++ni) {
                int n = n0 + wn + ni * 16 + r16;
                float mn = (colNeg[n - n0] == 0.f) ? 1.f : 0.f;
#pragma unroll
                for (int r = 0; r < 4; ++r) {
                    int m = m0 + wm + mi * 16 + quad * 4 + r;
                    float mm = (rowNeg[m - m0] == 0.f) ? 1.f : 0.f;
                    o2[(size_t)m * 512 + n] = (m > n) ? 0.f : (mm * mn);
                }
            }
    }
}

// ---------------------------------------------------------------------------
extern "C" void kernel_launch(void* const* d_in, const int* in_sizes, int n_in,
                              void* d_out, int out_size, void* d_ws, size_t ws_size,
                              hipStream_t stream) {
    const float* hidden = (const float*)d_in[0];   // (8,512,768) fp32
    const int*   tok    = (const int*)d_in[1];     // (8,512) int32
    const float* W      = (const float*)d_in[2];   // (768,2048) fp32
    const float* bias   = (const float*)d_in[3];   // (2048,) fp32
    float* out  = (float*)d_out;                   // logits: 33,554,432 floats
    float* out2 = out + 33554432;                  // tri_mask: 2,097,152 floats

    // workspace layout (~26.3 MiB):
    //   [0, 6.29M)        Xb   bf16 4096x768
    //   [6.29M, +3.15M)   Wt   bf16 2048x768
    //   [9.44M, +64K)     SinT fp32 512x32
    //   [9.50M, +64K)     CosT fp32 512x32
    //   [9.57M, +8.39M)   Qb   bf16 (B,H,S,64)
    //   [17.96M, +8.39M)  Kb   bf16 (B,H,S,64)
    char* ws = (char*)d_ws;
    short* Xb   = (short*)(ws);
    short* Wt   = (short*)(ws + 6291456);
    float* SinT = (float*)(ws + 9437184);
    float* CosT = (float*)(ws + 9502720);
    short* Qb   = (short*)(ws + 9568256);
    short* Kb   = (short*)(ws + 17956864);

    hipLaunchKernelGGL(prep_kernel,   dim3(1984), dim3(256), 0, stream,
                       hidden, W, Xb, Wt, SinT, CosT);
    hipLaunchKernelGGL(gemm_rope,     dim3(1024), dim3(256), 0, stream,
                       Xb, Wt, bias, SinT, CosT, Qb, Kb);
    hipLaunchKernelGGL(logits_kernel, dim3(2048), dim3(256), 0, stream,
                       Qb, Kb, tok, out, out2);
}

// Round 7
// 186.378 us; speedup vs baseline: 1.0191x; 1.0191x over previous
//
#include <hip/hip_runtime.h>
#include <hip/hip_bf16.h>
#include <cstdint>
#include <cstddef>

// B=8, S=512, D=768, HEADS=16, HD=64
// Pipeline (3 kernels):
//   prep:      cast hidden->bf16, sincos table, LDS-tiled W transpose->Wt bf16
//   gemm_rope: 4096x2048x768 bf16 MFMA + bias + RoPE (shfl_xor pair) epilogue,
//              writes Q,K head-major (b,h,s,64) bf16
//   logits:    128 batched 512x512x64 MFMA, global_load_lds + XOR-swizzled LDS,
//              mask epilogue, tri_mask fused into h==0 blocks
// Tolerance ~2e10 absmax (NEG=1e12) -> bf16 numerically free.
// R5: nt stores reverted (208.4 -> 193.7; nt defeats L2 write-combining).
// R6: XCD swizzle: 190.1.  R7: BK=64: 185.2 (-4.9, drain-cost theory held).
// R8 FAILED: 128x64 tile doubled A staging traffic (100->200MB), +4.7us.
//     Reverted to R7 gemm_rope.
// R9: logits causal-tile skip: mt>nt blocks are fully masked (m>n for all
//     elements); drop the qk/8 term (error <= |qk|/8 ~2 vs 1e12 values,
//     tolerance ~2e10) -> 768 of 2048 blocks become pure write-out: no
//     staging, no MFMA, no drains. absmax will rise to O(1-3) by design.

#define NEGV 1.0e12f

typedef short bf16x8 __attribute__((ext_vector_type(8)));
typedef float f32x4  __attribute__((ext_vector_type(4)));

static __device__ __forceinline__ short f2b(float x) {
    __hip_bfloat16 h = __float2bfloat16(x);
    union { __hip_bfloat16 h; short s; } u; u.h = h; return u.s;
}
static __device__ __forceinline__ float b2f(short s) {
    union { short s; __hip_bfloat16 h; } u; u.s = s; return __bfloat162float(u.h);
}
// async global->LDS: per-lane global addr, LDS dest = wave-uniform base + lane*16
static __device__ __forceinline__ void gload16(const short* g, short* l) {
    __builtin_amdgcn_global_load_lds(
        (const __attribute__((address_space(1))) void*)g,
        (__attribute__((address_space(3))) void*)l, 16, 0, 0);
}

// ---------------------------------------------------------------------------
// 1) prep: blocks [0,1536) cast hidden; [1536,1600) sincos table;
//          [1600,1984) 64x64 LDS-tiled W transpose (fp32 KxN -> bf16 NxK)
// ---------------------------------------------------------------------------
__global__ __launch_bounds__(256) void prep_kernel(const float* __restrict__ hidden,
                                                   const float* __restrict__ W,
                                                   short* __restrict__ Xb,
                                                   short* __restrict__ Wt,
                                                   float* __restrict__ SinT,
                                                   float* __restrict__ CosT) {
    __shared__ short T[64 * 68];
    int blk = blockIdx.x, tid = threadIdx.x;
    if (blk < 1536) {                          // 393,216 threads x 8 floats
        int t = blk * 256 + tid;
        const float4* hp = (const float4*)hidden;
        float4 a = hp[t * 2], c = hp[t * 2 + 1];
        bf16x8 v;
        v[0] = f2b(a.x); v[1] = f2b(a.y); v[2] = f2b(a.z); v[3] = f2b(a.w);
        v[4] = f2b(c.x); v[5] = f2b(c.y); v[6] = f2b(c.z); v[7] = f2b(c.w);
        *(bf16x8*)(Xb + t * 8) = v;
    } else if (blk < 1600) {                   // 16,384 table entries
        int u = (blk - 1536) * 256 + tid;
        int s = u >> 5, i = u & 31;
        float ang = (float)s * exp2f(-0.4152410118609203f * (float)i); // log2(1e4)/32
        float sn, cs; __sincosf(ang, &sn, &cs);
        SinT[u] = sn; CosT[u] = cs;
    } else {                                   // 384 transpose tiles
        int tb = blk - 1600;
        int k0 = (tb % 12) * 64, n0 = (tb / 12) * 64;
        int r = tid >> 2, cb = (tid & 3) * 4;
#pragma unroll
        for (int q = 0; q < 4; ++q) {
            int c = cb + q * 16;
            float4 v = *(const float4*)(W + (size_t)(k0 + r) * 2048 + n0 + c);
            short* tp = T + r * 68 + c;
            tp[0] = f2b(v.x); tp[1] = f2b(v.y); tp[2] = f2b(v.z); tp[3] = f2b(v.w);
        }
        __syncthreads();
        int n = tid >> 2, kc = (tid & 3) * 16;
        bf16x8 o0, o1;
#pragma unroll
        for (int j = 0; j < 8; ++j) {
            o0[j] = T[(kc + j) * 68 + n];
            o1[j] = T[(kc + 8 + j) * 68 + n];
        }
        short* wp = Wt + (size_t)(n0 + n) * 768 + k0 + kc;
        *(bf16x8*)wp = o0;
        *(bf16x8*)(wp + 8) = o1;
    }
}

// ---------------------------------------------------------------------------
// 2) gemm_rope: C=A@Wt^T+bias (4096x2048x768), 128x128 tile, BK=64 (R7),
//    global_load_lds staging, 2 barriers per K-iter (12 iters).
//    LDS rows 64 shorts (128B); XOR swizzle: LDS row r position p holds global
//    chunk p^(r&7); staged via pre-swizzled global src chunk ((l&7)^(l>>3)),
//    read at chunk (kk*4+quad)^(r16&7) -> 2-way bank conflicts (free).
//    Epilogue: bias + RoPE via __shfl_xor(v,1), store Q/K head-major bf16.
//    XCD-chunked wgid swizzle (512 = 8 XCD * 64).
// ---------------------------------------------------------------------------
__global__ __launch_bounds__(256) void gemm_rope(const short* __restrict__ A,
                                                 const short* __restrict__ Bt,
                                                 const float* __restrict__ bias,
                                                 const float* __restrict__ SinT,
                                                 const float* __restrict__ CosT,
                                                 short* __restrict__ Qb,
                                                 short* __restrict__ Kb) {
    __shared__ short As[128 * 64];
    __shared__ short Bs[128 * 64];
    const int blk = (blockIdx.x & 7) * 64 + (blockIdx.x >> 3);  // XCD-chunked
    const int m0 = (blk >> 4) * 128;          // 32 m-tiles
    const int n0 = (blk & 15) * 128;          // 16 n-tiles
    const int tid  = threadIdx.x;
    const int wave = tid >> 6, lane = tid & 63;
    const int quad = lane >> 4, r16 = lane & 15;
    const int wm = (wave >> 1) * 64, wn = (wave & 1) * 64;

    // staging: per call j (4 calls for A, 4 for B), wave w covers rows
    // j*32 + w*8 + (l>>3); global chunk pre-swizzled: (l&7)^(l>>3).
    const int sc  = ((lane & 7) ^ (lane >> 3)) * 8;   // shorts
    const int rst = wave * 8 + (lane >> 3);           // row within 32-row group
    const short* gA = A  + (size_t)(m0 + rst) * 768 + sc;
    const short* gB = Bt + (size_t)(n0 + rst) * 768 + sc;
    short* lA = As + (wave * 8) * 64;                 // wave-uniform LDS base
    short* lB = Bs + (wave * 8) * 64;

    const int sw8 = r16 & 7;                  // frag-read swizzle key (row&7)

    f32x4 acc[4][4] = {};
    for (int k0 = 0; k0 < 768; k0 += 64) {
        __syncthreads();                      // protect LDS overwrite
#pragma unroll
        for (int j = 0; j < 4; ++j) {
            gload16(gA + (size_t)j * 32 * 768 + k0, lA + j * 32 * 64);
            gload16(gB + (size_t)j * 32 * 768 + k0, lB + j * 32 * 64);
        }
        __syncthreads();                      // vmcnt drain: tile ready

#pragma unroll
        for (int kk = 0; kk < 2; ++kk) {
            bf16x8 af[4], bfr[4];
#pragma unroll
            for (int mi = 0; mi < 4; ++mi)
                af[mi] = *(const bf16x8*)(As + (wm + mi * 16 + r16) * 64
                                             + ((kk * 4 + quad) ^ sw8) * 8);
#pragma unroll
            for (int ni = 0; ni < 4; ++ni)
                bfr[ni] = *(const bf16x8*)(Bs + (wn + ni * 16 + r16) * 64
                                              + ((kk * 4 + quad) ^ sw8) * 8);
#pragma unroll
            for (int mi = 0; mi < 4; ++mi)
#pragma unroll
                for (int ni = 0; ni < 4; ++ni)
                    acc[mi][ni] = __builtin_amdgcn_mfma_f32_16x16x32_bf16(
                        af[mi], bfr[ni], acc[mi][ni], 0, 0, 0);
        }
    }

    // epilogue: bias + RoPE + head-major store
    const int b     = m0 >> 9;
    const int s0l   = (m0 & 511) + wm + quad * 4;
    const int h     = n0 >> 7;                 // n0 in [0,2048): h = n0/128
    const int which = wn >> 6;                 // 0 -> Q half, 1 -> K half
    short* dstT = (which ? Kb : Qb) + (size_t)(b * 16 + h) * 512 * 64;
    const float sgn = (r16 & 1) ? 1.0f : -1.0f;
#pragma unroll
    for (int ni = 0; ni < 4; ++ni) {
        int col = n0 + wn + ni * 16 + r16;
        float bv = bias[col];
        int d  = ni * 16 + r16;
        int ii = d >> 1;
#pragma unroll
        for (int mi = 0; mi < 4; ++mi)
#pragma unroll
            for (int r = 0; r < 4; ++r) {
                int s = s0l + mi * 16 + r;
                float v  = acc[mi][ni][r] + bv;
                float pv = __shfl_xor(v, 1);   // partner element of the RoPE pair
                float sn = SinT[s * 32 + ii];
                float cs = CosT[s * 32 + ii];
                dstT[(size_t)s * 64 + d] = f2b(v * cs + sgn * pv * sn);
            }
    }
}

// ---------------------------------------------------------------------------
// 3) logits: per (b,h, 128x128 tile) Q@K^T (K=64). global_load_lds staging,
//    XOR swizzle chunk(r,c)->r*8+(c^(r&7)) -> 2-way frag reads (free).
//    Epilogue: /8 - rowNeg - colNeg - causal; tri_mask fused at h==0.
//    R9: mt>nt tiles are fully causal-masked -> skip staging+MFMA, write
//    v = -rowNeg-colNeg-NEGV directly (drop qk/8; error ~2 vs tol ~2e10).
//    XCD-chunked wgid swizzle (2048 = 8 XCD * 256).
// ---------------------------------------------------------------------------
__global__ __launch_bounds__(256) void logits_kernel(const short* __restrict__ Qb,
                                                     const short* __restrict__ Kb,
                                                     const int* __restrict__ tok,
                                                     float* __restrict__ out,
                                                     float* __restrict__ out2) {
    __shared__ short Qs[128 * 64];
    __shared__ short Ks[128 * 64];
    __shared__ float rowNeg[128];
    __shared__ float colNeg[128];

    int blk = (blockIdx.x & 7) * 256 + (blockIdx.x >> 3);  // XCD-chunked
    int nt = blk & 3, mt = (blk >> 2) & 3, bh = blk >> 4;
    int b = bh >> 4, h = bh & 15;
    int m0 = mt * 128, n0 = nt * 128;

    const int tid  = threadIdx.x;
    const int wave = tid >> 6, lane = tid & 63;
    const int quad = lane >> 4, r16 = lane & 15;
    const int wm = (wave >> 1) * 64, wn = (wave & 1) * 64;

    if (mt > nt) {
        // Fully causal-masked tile: every (m,n) has m > n. Output is
        // qk/8 - rowNeg - colNeg - NEGV; we drop qk/8 (|qk|/8 ~ 2, vs
        // 1e12-magnitude values and ~2e10 tolerance). Pure write-out block.
        if (tid < 128)      rowNeg[tid]       = (tok[b * 512 + m0 + tid] > 0) ? 0.f : NEGV;
        else if (tid < 256) colNeg[tid - 128] = (tok[b * 512 + n0 + (tid - 128)] > 0) ? 0.f : NEGV;
        __syncthreads();
        float* obase = out + (size_t)bh * 512 * 512;
#pragma unroll
        for (int mi = 0; mi < 4; ++mi)
#pragma unroll
            for (int ni = 0; ni < 4; ++ni) {
                int n = n0 + wn + ni * 16 + r16;
                float cn = colNeg[n - n0];
#pragma unroll
                for (int r = 0; r < 4; ++r) {
                    int m = m0 + wm + mi * 16 + quad * 4 + r;
                    obase[(size_t)m * 512 + n] = -rowNeg[m - m0] - cn - NEGV;
                }
            }
        if (h == 0) {    // tri_mask: all zero here (m > n everywhere)
            float* o2 = out2 + (size_t)b * 512 * 512;
#pragma unroll
            for (int mi = 0; mi < 4; ++mi)
#pragma unroll
                for (int ni = 0; ni < 4; ++ni) {
                    int n = n0 + wn + ni * 16 + r16;
#pragma unroll
                    for (int r = 0; r < 4; ++r) {
                        int m = m0 + wm + mi * 16 + quad * 4 + r;
                        o2[(size_t)m * 512 + n] = 0.f;
                    }
                }
        }
        return;
    }

    // staging: waves 0,1 -> Q; waves 2,3 -> K. 8 calls x 64 chunks each.
    const short* gsrc = (wave < 2)
        ? Qb + ((size_t)bh * 512 + m0) * 64
        : Kb + ((size_t)bh * 512 + n0) * 64;
    short* ldst = (wave < 2) ? Qs : Ks;
    const int wv = wave & 1;
    const int gc = ((lane & 7) ^ (lane >> 3)) * 8;   // swizzled chunk col, shorts
    const int rl = wv * 64 + (lane >> 3);            // + j*8 per call
#pragma unroll
    for (int j = 0; j < 8; ++j)
        gload16(gsrc + (rl + j * 8) * 64 + gc, ldst + wv * 4096 + j * 512);

    if (tid < 128)      rowNeg[tid]       = (tok[b * 512 + m0 + tid] > 0) ? 0.f : NEGV;
    else if (tid < 256) colNeg[tid - 128] = (tok[b * 512 + n0 + (tid - 128)] > 0) ? 0.f : NEGV;
    __syncthreads();

    const int sw8 = r16 & 7;              // frag swizzle key (r&7 == r16&7)
    f32x4 acc[4][4] = {};
#pragma unroll
    for (int kb = 0; kb < 2; ++kb) {      // kk = kb*32 -> chunkcol quad + kb*4
        bf16x8 af[4], bfr[4];
#pragma unroll
        for (int mi = 0; mi < 4; ++mi)
            af[mi] = *(const bf16x8*)(Qs + (wm + mi * 16 + r16) * 64
                                         + ((quad + kb * 4) ^ sw8) * 8);
#pragma unroll
        for (int ni = 0; ni < 4; ++ni)
            bfr[ni] = *(const bf16x8*)(Ks + (wn + ni * 16 + r16) * 64
                                          + ((quad + kb * 4) ^ sw8) * 8);
#pragma unroll
        for (int mi = 0; mi < 4; ++mi)
#pragma unroll
            for (int ni = 0; ni < 4; ++ni)
                acc[mi][ni] = __builtin_amdgcn_mfma_f32_16x16x32_bf16(
                    af[mi], bfr[ni], acc[mi][ni], 0, 0, 0);
    }

    float* obase = out + (size_t)bh * 512 * 512;
#pragma unroll
    for (int mi = 0; mi < 4; ++mi)
#pragma unroll
        for (int ni = 0; ni < 4; ++ni) {
            int n = n0 + wn + ni * 16 + r16;
            float cn = colNeg[n - n0];
#pragma unroll
            for (int r = 0; r < 4; ++r) {
                int m = m0 + wm + mi * 16 + quad * 4 + r;
                float v = acc[mi][ni][r] * 0.125f - rowNeg[m - m0] - cn
                          - ((m > n) ? NEGV : 0.0f);
                obase[(size_t)m * 512 + n] = v;
            }
        }

    if (h == 0) {    // fused tri_mask
        float* o2 = out2 + (size_t)b * 512 * 512;
#pragma unroll
        for (int mi = 0; mi < 4; ++mi)
#pragma unroll
            for (int ni = 0; ni < 4; ++ni) {
                int n = n0 + wn + ni * 16 + r16;
                float mn = (colNeg[n - n0] == 0.f) ? 1.f : 0.f;
#pragma unroll
                for (int r = 0; r < 4; ++r) {
                    int m = m0 + wm + mi * 16 + quad * 4 + r;
                    float mm = (rowNeg[m - m0] == 0.f) ? 1.f : 0.f;
                    o2[(size_t)m * 512 + n] = (m > n) ? 0.f : (mm * mn);
                }
            }
    }
}

// ---------------------------------------------------------------------------
extern "C" void kernel_launch(void* const* d_in, const int* in_sizes, int n_in,
                              void* d_out, int out_size, void* d_ws, size_t ws_size,
                              hipStream_t stream) {
    const float* hidden = (const float*)d_in[0];   // (8,512,768) fp32
    const int*   tok    = (const int*)d_in[1];     // (8,512) int32
    const float* W      = (const float*)d_in[2];   // (768,2048) fp32
    const float* bias   = (const float*)d_in[3];   // (2048,) fp32
    float* out  = (float*)d_out;                   // logits: 33,554,432 floats
    float* out2 = out + 33554432;                  // tri_mask: 2,097,152 floats

    // workspace layout (~26.3 MiB):
    //   [0, 6.29M)        Xb   bf16 4096x768
    //   [6.29M, +3.15M)   Wt   bf16 2048x768
    //   [9.44M, +64K)     SinT fp32 512x32
    //   [9.50M, +64K)     CosT fp32 512x32
    //   [9.57M, +8.39M)   Qb   bf16 (B,H,S,64)
    //   [17.96M, +8.39M)  Kb   bf16 (B,H,S,64)
    char* ws = (char*)d_ws;
    short* Xb   = (short*)(ws);
    short* Wt   = (short*)(ws + 6291456);
    float* SinT = (float*)(ws + 9437184);
    float* CosT = (float*)(ws + 9502720);
    short* Qb   = (short*)(ws + 9568256);
    short* Kb   = (short*)(ws + 17956864);

    hipLaunchKernelGGL(prep_kernel,   dim3(1984), dim3(256), 0, stream,
                       hidden, W, Xb, Wt, SinT, CosT);
    hipLaunchKernelGGL(gemm_rope,     dim3(512),  dim3(256), 0, stream,
                       Xb, Wt, bias, SinT, CosT, Qb, Kb);
    hipLaunchKernelGGL(logits_kernel, dim3(2048), dim3(256), 0, stream,
                       Qb, Kb, tok, out, out2);
}

// Round 8
// 181.815 us; speedup vs baseline: 1.0446x; 1.0251x over previous
//
#include <hip/hip_runtime.h>
#include <hip/hip_bf16.h>
#include <cstdint>
#include <cstddef>

// B=8, S=512, D=768, HEADS=16, HD=64
// Pipeline (3 kernels):
//   prep:      cast hidden->bf16, sincos table, LDS-tiled W transpose->Wt bf16
//   gemm_rope: 4096x2048x768 bf16 MFMA + bias + RoPE (shfl_xor pair) epilogue,
//              writes Q,K head-major (b,h,s,64) bf16
//   logits:    128 batched 512x512x64 MFMA, global_load_lds + XOR-swizzled LDS,
//              mask epilogue, tri_mask fused into h==0 blocks
// R5: nt stores reverted (208.4 -> 193.7; nt defeats L2 write-combining).
// R6: XCD swizzle: 190.1.  R7: BK=64: 185.2 (-4.9, drain-cost theory held).
// R8 FAILED: 128x64 tile doubled A staging traffic; reverted.
// R9: logits causal-tile skip (mt>nt): NEUTRAL perf (logits is write-bound)
//     but numerically LOSSLESS (ULP(1e12)=65536 >> |qk|/8) -> kept.
// R10: gemm_rope T4 counted-vmcnt pipeline: double-buffer LDS, raw s_barrier,
//     s_waitcnt vmcnt(8) in-loop (never 0 until last iter). Tile t+1's 8
//     loads stay in flight across the wait; stage(t+2) issued after the
//     read-complete barrier. Kills the 12 remaining full drains (~5us, R7
//     scaling). LDS 64KB -> 2 blocks/CU (grid-limited anyway).

#define NEGV 1.0e12f

typedef short bf16x8 __attribute__((ext_vector_type(8)));
typedef float f32x4  __attribute__((ext_vector_type(4)));

static __device__ __forceinline__ short f2b(float x) {
    __hip_bfloat16 h = __float2bfloat16(x);
    union { __hip_bfloat16 h; short s; } u; u.h = h; return u.s;
}
static __device__ __forceinline__ float b2f(short s) {
    union { short s; __hip_bfloat16 h; } u; u.s = s; return __bfloat162float(u.h);
}
// async global->LDS: per-lane global addr, LDS dest = wave-uniform base + lane*16
static __device__ __forceinline__ void gload16(const short* g, short* l) {
    __builtin_amdgcn_global_load_lds(
        (const __attribute__((address_space(1))) void*)g,
        (__attribute__((address_space(3))) void*)l, 16, 0, 0);
}

// ---------------------------------------------------------------------------
// 1) prep: blocks [0,1536) cast hidden; [1536,1600) sincos table;
//          [1600,1984) 64x64 LDS-tiled W transpose (fp32 KxN -> bf16 NxK)
// ---------------------------------------------------------------------------
__global__ __launch_bounds__(256) void prep_kernel(const float* __restrict__ hidden,
                                                   const float* __restrict__ W,
                                                   short* __restrict__ Xb,
                                                   short* __restrict__ Wt,
                                                   float* __restrict__ SinT,
                                                   float* __restrict__ CosT) {
    __shared__ short T[64 * 68];
    int blk = blockIdx.x, tid = threadIdx.x;
    if (blk < 1536) {                          // 393,216 threads x 8 floats
        int t = blk * 256 + tid;
        const float4* hp = (const float4*)hidden;
        float4 a = hp[t * 2], c = hp[t * 2 + 1];
        bf16x8 v;
        v[0] = f2b(a.x); v[1] = f2b(a.y); v[2] = f2b(a.z); v[3] = f2b(a.w);
        v[4] = f2b(c.x); v[5] = f2b(c.y); v[6] = f2b(c.z); v[7] = f2b(c.w);
        *(bf16x8*)(Xb + t * 8) = v;
    } else if (blk < 1600) {                   // 16,384 table entries
        int u = (blk - 1536) * 256 + tid;
        int s = u >> 5, i = u & 31;
        float ang = (float)s * exp2f(-0.4152410118609203f * (float)i); // log2(1e4)/32
        float sn, cs; __sincosf(ang, &sn, &cs);
        SinT[u] = sn; CosT[u] = cs;
    } else {                                   // 384 transpose tiles
        int tb = blk - 1600;
        int k0 = (tb % 12) * 64, n0 = (tb / 12) * 64;
        int r = tid >> 2, cb = (tid & 3) * 4;
#pragma unroll
        for (int q = 0; q < 4; ++q) {
            int c = cb + q * 16;
            float4 v = *(const float4*)(W + (size_t)(k0 + r) * 2048 + n0 + c);
            short* tp = T + r * 68 + c;
            tp[0] = f2b(v.x); tp[1] = f2b(v.y); tp[2] = f2b(v.z); tp[3] = f2b(v.w);
        }
        __syncthreads();
        int n = tid >> 2, kc = (tid & 3) * 16;
        bf16x8 o0, o1;
#pragma unroll
        for (int j = 0; j < 8; ++j) {
            o0[j] = T[(kc + j) * 68 + n];
            o1[j] = T[(kc + 8 + j) * 68 + n];
        }
        short* wp = Wt + (size_t)(n0 + n) * 768 + k0 + kc;
        *(bf16x8*)wp = o0;
        *(bf16x8*)(wp + 8) = o1;
    }
}

// ---------------------------------------------------------------------------
// 2) gemm_rope: C=A@Wt^T+bias (4096x2048x768), 128x128 tile, BK=64,
//    R10 counted-vmcnt double-buffer pipeline (T4):
//      prologue stage(0->b0), stage(1->b1)   [16 loads/wave in flight]
//      iter t: vmcnt(8) [tile t done, t+1 in flight] ; s_barrier ;
//              ds_read+MFMA(b[t&1]) ; s_barrier ; stage(t+2 -> b[t&1])
//    LDS rows 64 shorts (128B), XOR swizzle: row r pos p holds chunk p^(r&7)
//    (pre-swizzled global src, frag read chunk (kk*4+quad)^(r16&7) -> 2-way).
//    Epilogue: bias + RoPE via __shfl_xor(v,1), store Q/K head-major bf16.
//    XCD-chunked wgid swizzle (512 = 8 XCD * 64).
// ---------------------------------------------------------------------------
__global__ __launch_bounds__(256) void gemm_rope(const short* __restrict__ A,
                                                 const short* __restrict__ Bt,
                                                 const float* __restrict__ bias,
                                                 const float* __restrict__ SinT,
                                                 const float* __restrict__ CosT,
                                                 short* __restrict__ Qb,
                                                 short* __restrict__ Kb) {
    __shared__ short As[2][128 * 64];
    __shared__ short Bs[2][128 * 64];
    const int blk = (blockIdx.x & 7) * 64 + (blockIdx.x >> 3);  // XCD-chunked
    const int m0 = (blk >> 4) * 128;          // 32 m-tiles
    const int n0 = (blk & 15) * 128;          // 16 n-tiles
    const int tid  = threadIdx.x;
    const int wave = tid >> 6, lane = tid & 63;
    const int quad = lane >> 4, r16 = lane & 15;
    const int wm = (wave >> 1) * 64, wn = (wave & 1) * 64;

    // staging: call j covers rows j*32 + wave*8 + (l>>3);
    // global chunk pre-swizzled: (l&7)^(l>>3); LDS dest linear.
    const int sc  = ((lane & 7) ^ (lane >> 3)) * 8;   // shorts
    const int rst = wave * 8 + (lane >> 3);           // row within 32-row group
    const short* gA = A  + (size_t)(m0 + rst) * 768 + sc;
    const short* gB = Bt + (size_t)(n0 + rst) * 768 + sc;
    const int lbase = (wave * 8) * 64;                // wave-uniform LDS base

    const int sw8 = r16 & 7;                  // frag-read swizzle key (row&7)

    f32x4 acc[4][4] = {};

    auto stage = [&](int t, int buf) {
        const int k0 = t * 64;
#pragma unroll
        for (int j = 0; j < 4; ++j) {
            gload16(gA + (size_t)(j * 32) * 768 + k0, As[buf] + lbase + j * 32 * 64);
            gload16(gB + (size_t)(j * 32) * 768 + k0, Bs[buf] + lbase + j * 32 * 64);
        }
    };

    // prologue: tiles 0 and 1 in flight (8 loads/wave each)
    stage(0, 0);
    stage(1, 1);

#pragma unroll
    for (int t = 0; t < 12; ++t) {
        const int cur = t & 1;
        if (t < 11) { asm volatile("s_waitcnt vmcnt(8)" ::: "memory"); }
        else        { asm volatile("s_waitcnt vmcnt(0)" ::: "memory"); }
        __builtin_amdgcn_sched_barrier(0);
        __builtin_amdgcn_s_barrier();          // all waves: tile t resident

#pragma unroll
        for (int kk = 0; kk < 2; ++kk) {
            bf16x8 af[4], bfr[4];
#pragma unroll
            for (int mi = 0; mi < 4; ++mi)
                af[mi] = *(const bf16x8*)(As[cur] + (wm + mi * 16 + r16) * 64
                                             + ((kk * 4 + quad) ^ sw8) * 8);
#pragma unroll
            for (int ni = 0; ni < 4; ++ni)
                bfr[ni] = *(const bf16x8*)(Bs[cur] + (wn + ni * 16 + r16) * 64
                                              + ((kk * 4 + quad) ^ sw8) * 8);
#pragma unroll
            for (int mi = 0; mi < 4; ++mi)
#pragma unroll
                for (int ni = 0; ni < 4; ++ni)
                    acc[mi][ni] = __builtin_amdgcn_mfma_f32_16x16x32_bf16(
                        af[mi], bfr[ni], acc[mi][ni], 0, 0, 0);
        }

        __builtin_amdgcn_s_barrier();          // all waves done reading buf[cur]
        if (t + 2 < 12) stage(t + 2, cur);     // overwrite now safe; async
    }

    // epilogue: bias + RoPE + head-major store
    const int b     = m0 >> 9;
    const int s0l   = (m0 & 511) + wm + quad * 4;
    const int h     = n0 >> 7;                 // n0 in [0,2048): h = n0/128
    const int which = wn >> 6;                 // 0 -> Q half, 1 -> K half
    short* dstT = (which ? Kb : Qb) + (size_t)(b * 16 + h) * 512 * 64;
    const float sgn = (r16 & 1) ? 1.0f : -1.0f;
#pragma unroll
    for (int ni = 0; ni < 4; ++ni) {
        int col = n0 + wn + ni * 16 + r16;
        float bv = bias[col];
        int d  = ni * 16 + r16;
        int ii = d >> 1;
#pragma unroll
        for (int mi = 0; mi < 4; ++mi)
#pragma unroll
            for (int r = 0; r < 4; ++r) {
                int s = s0l + mi * 16 + r;
                float v  = acc[mi][ni][r] + bv;
                float pv = __shfl_xor(v, 1);   // partner element of the RoPE pair
                float sn = SinT[s * 32 + ii];
                float cs = CosT[s * 32 + ii];
                dstT[(size_t)s * 64 + d] = f2b(v * cs + sgn * pv * sn);
            }
    }
}

// ---------------------------------------------------------------------------
// 3) logits: per (b,h, 128x128 tile) Q@K^T (K=64). global_load_lds staging,
//    XOR swizzle chunk(r,c)->r*8+(c^(r&7)) -> 2-way frag reads (free).
//    Epilogue: /8 - rowNeg - colNeg - causal; tri_mask fused at h==0.
//    R9: mt>nt tiles fully causal-masked -> skip staging+MFMA, write
//    -rowNeg-colNeg-NEGV directly (lossless: ULP(1e12) >> |qk|/8).
//    XCD-chunked wgid swizzle (2048 = 8 XCD * 256).
// ---------------------------------------------------------------------------
__global__ __launch_bounds__(256) void logits_kernel(const short* __restrict__ Qb,
                                                     const short* __restrict__ Kb,
                                                     const int* __restrict__ tok,
                                                     float* __restrict__ out,
                                                     float* __restrict__ out2) {
    __shared__ short Qs[128 * 64];
    __shared__ short Ks[128 * 64];
    __shared__ float rowNeg[128];
    __shared__ float colNeg[128];

    int blk = (blockIdx.x & 7) * 256 + (blockIdx.x >> 3);  // XCD-chunked
    int nt = blk & 3, mt = (blk >> 2) & 3, bh = blk >> 4;
    int b = bh >> 4, h = bh & 15;
    int m0 = mt * 128, n0 = nt * 128;

    const int tid  = threadIdx.x;
    const int wave = tid >> 6, lane = tid & 63;
    const int quad = lane >> 4, r16 = lane & 15;
    const int wm = (wave >> 1) * 64, wn = (wave & 1) * 64;

    if (mt > nt) {
        // Fully causal-masked tile. Pure write-out block (drop qk/8: below
        // fp32 ULP at 1e12 magnitude -> bit-identical output).
        if (tid < 128)      rowNeg[tid]       = (tok[b * 512 + m0 + tid] > 0) ? 0.f : NEGV;
        else if (tid < 256) colNeg[tid - 128] = (tok[b * 512 + n0 + (tid - 128)] > 0) ? 0.f : NEGV;
        __syncthreads();
        float* obase = out + (size_t)bh * 512 * 512;
#pragma unroll
        for (int mi = 0; mi < 4; ++mi)
#pragma unroll
            for (int ni = 0; ni < 4; ++ni) {
                int n = n0 + wn + ni * 16 + r16;
                float cn = colNeg[n - n0];
#pragma unroll
                for (int r = 0; r < 4; ++r) {
                    int m = m0 + wm + mi * 16 + quad * 4 + r;
                    obase[(size_t)m * 512 + n] = -rowNeg[m - m0] - cn - NEGV;
                }
            }
        if (h == 0) {    // tri_mask: all zero here (m > n everywhere)
            float* o2 = out2 + (size_t)b * 512 * 512;
#pragma unroll
            for (int mi = 0; mi < 4; ++mi)
#pragma unroll
                for (int ni = 0; ni < 4; ++ni) {
                    int n = n0 + wn + ni * 16 + r16;
#pragma unroll
                    for (int r = 0; r < 4; ++r) {
                        int m = m0 + wm + mi * 16 + quad * 4 + r;
                        o2[(size_t)m * 512 + n] = 0.f;
                    }
                }
        }
        return;
    }

    // staging: waves 0,1 -> Q; waves 2,3 -> K. 8 calls x 64 chunks each.
    const short* gsrc = (wave < 2)
        ? Qb + ((size_t)bh * 512 + m0) * 64
        : Kb + ((size_t)bh * 512 + n0) * 64;
    short* ldst = (wave < 2) ? Qs : Ks;
    const int wv = wave & 1;
    const int gc = ((lane & 7) ^ (lane >> 3)) * 8;   // swizzled chunk col, shorts
    const int rl = wv * 64 + (lane >> 3);            // + j*8 per call
#pragma unroll
    for (int j = 0; j < 8; ++j)
        gload16(gsrc + (rl + j * 8) * 64 + gc, ldst + wv * 4096 + j * 512);

    if (tid < 128)      rowNeg[tid]       = (tok[b * 512 + m0 + tid] > 0) ? 0.f : NEGV;
    else if (tid < 256) colNeg[tid - 128] = (tok[b * 512 + n0 + (tid - 128)] > 0) ? 0.f : NEGV;
    __syncthreads();

    const int sw8 = r16 & 7;              // frag swizzle key (r&7 == r16&7)
    f32x4 acc[4][4] = {};
#pragma unroll
    for (int kb = 0; kb < 2; ++kb) {      // kk = kb*32 -> chunkcol quad + kb*4
        bf16x8 af[4], bfr[4];
#pragma unroll
        for (int mi = 0; mi < 4; ++mi)
            af[mi] = *(const bf16x8*)(Qs + (wm + mi * 16 + r16) * 64
                                         + ((quad + kb * 4) ^ sw8) * 8);
#pragma unroll
        for (int ni = 0; ni < 4; ++ni)
            bfr[ni] = *(const bf16x8*)(Ks + (wn + ni * 16 + r16) * 64
                                          + ((quad + kb * 4) ^ sw8) * 8);
#pragma unroll
        for (int mi = 0; mi < 4; ++mi)
#pragma unroll
            for (int ni = 0; ni < 4; ++ni)
                acc[mi][ni] = __builtin_amdgcn_mfma_f32_16x16x32_bf16(
                    af[mi], bfr[ni], acc[mi][ni], 0, 0, 0);
    }

    float* obase = out + (size_t)bh * 512 * 512;
#pragma unroll
    for (int mi = 0; mi < 4; ++mi)
#pragma unroll
        for (int ni = 0; ni < 4; ++ni) {
            int n = n0 + wn + ni * 16 + r16;
            float cn = colNeg[n - n0];
#pragma unroll
            for (int r = 0; r < 4; ++r) {
                int m = m0 + wm + mi * 16 + quad * 4 + r;
                float v = acc[mi][ni][r] * 0.125f - rowNeg[m - m0] - cn
                          - ((m > n) ? NEGV : 0.0f);
                obase[(size_t)m * 512 + n] = v;
            }
        }

    if (h == 0) {    // fused tri_mask
        float* o2 = out2 + (size_t)b * 512 * 512;
#pragma unroll
        for (int mi = 0; mi < 4; ++mi)
#pragma unroll
            for (int ni = 0; ni < 4; ++ni) {
                int n = n0 + wn + ni * 16 + r16;
                float mn = (colNeg[n - n0] == 0.f) ? 1.f : 0.f;
#pragma unroll
                for (int r = 0; r < 4; ++r) {
                    int m = m0 + wm + mi * 16 + quad * 4 + r;
                    float mm = (rowNeg[m - m0] == 0.f) ? 1.f : 0.f;
                    o2[(size_t)m * 512 + n] = (m > n) ? 0.f : (mm * mn);
                }
            }
    }
}

// ---------------------------------------------------------------------------
extern "C" void kernel_launch(void* const* d_in, const int* in_sizes, int n_in,
                              void* d_out, int out_size, void* d_ws, size_t ws_size,
                              hipStream_t stream) {
    const float* hidden = (const float*)d_in[0];   // (8,512,768) fp32
    const int*   tok    = (const int*)d_in[1];     // (8,512) int32
    const float* W      = (const float*)d_in[2];   // (768,2048) fp32
    const float* bias   = (const float*)d_in[3];   // (2048,) fp32
    float* out  = (float*)d_out;                   // logits: 33,554,432 floats
    float* out2 = out + 33554432;                  // tri_mask: 2,097,152 floats

    // workspace layout (~26.3 MiB):
    //   [0, 6.29M)        Xb   bf16 4096x768
    //   [6.29M, +3.15M)   Wt   bf16 2048x768
    //   [9.44M, +64K)     SinT fp32 512x32
    //   [9.50M, +64K)     CosT fp32 512x32
    //   [9.57M, +8.39M)   Qb   bf16 (B,H,S,64)
    //   [17.96M, +8.39M)  Kb   bf16 (B,H,S,64)
    char* ws = (char*)d_ws;
    short* Xb   = (short*)(ws);
    short* Wt   = (short*)(ws + 6291456);
    float* SinT = (float*)(ws + 9437184);
    float* CosT = (float*)(ws + 9502720);
    short* Qb   = (short*)(ws + 9568256);
    short* Kb   = (short*)(ws + 17956864);

    hipLaunchKernelGGL(prep_kernel,   dim3(1984), dim3(256), 0, stream,
                       hidden, W, Xb, Wt, SinT, CosT);
    hipLaunchKernelGGL(gemm_rope,     dim3(512),  dim3(256), 0, stream,
                       Xb, Wt, bias, SinT, CosT, Qb, Kb);
    hipLaunchKernelGGL(logits_kernel, dim3(2048), dim3(256), 0, stream,
                       Qb, Kb, tok, out, out2);
}